// Round 1
// baseline (561.946 us; speedup 1.0000x reference)
//
#include <hip/hip_runtime.h>
#include <cstdint>

typedef __attribute__((ext_vector_type(8))) short bf16x8;
typedef __attribute__((ext_vector_type(4))) float f32x4;

__device__ __forceinline__ short f2b(float f) {
  unsigned u = __builtin_bit_cast(unsigned, f);
  unsigned r = (u + 0x7fffu + ((u >> 16) & 1u)) >> 16;
  return (short)(unsigned short)r;
}
__device__ __forceinline__ float b2f(short s) {
  unsigned u = ((unsigned)(unsigned short)s) << 16;
  return __builtin_bit_cast(float, u);
}

__device__ __forceinline__ void gload16(void* lds_dst, const void* gsrc) {
  __builtin_amdgcn_global_load_lds(
      (const __attribute__((address_space(1))) void*)gsrc,
      (__attribute__((address_space(3))) void*)lds_dst, 16, 0, 0);
}

// ---------------- weight conversion ----------------
// generic: src [rows][cols] f32 -> dst [cols][rows] bf16
__global__ void transpose_conv(const float* __restrict__ src, short* __restrict__ dst,
                               int rows, int cols)
{
  __shared__ float tl[32][33];
  const int bx = blockIdx.x, by = blockIdx.y;
  const int tx = threadIdx.x;
  const int x = bx * 32 + tx;
  for (int i2 = 0; i2 < 4; ++i2) {
    int i = threadIdx.y + i2 * 8;
    tl[i][tx] = src[(long)(by * 32 + i) * cols + x];
  }
  __syncthreads();
  const int xo = by * 32 + tx;
  for (int i2 = 0; i2 < 4; ++i2) {
    int i = threadIdx.y + i2 * 8;
    dst[(long)(bx * 32 + i) * rows + xo] = f2b(tl[tx][i]);
  }
}

// Wq/Wk/Wv [16][1024][64] f32 -> WqkvT [3072][1024] bf16, row j = which*1024+head*64+d
__global__ void qkv_pack(const float* __restrict__ Wq, const float* __restrict__ Wk,
                         const float* __restrict__ Wv, short* __restrict__ dst)
{
  __shared__ float tl[32][33];
  const int t = blockIdx.x;
  const int which = t >> 10;
  const int rem = t & 1023;
  const int head = rem >> 6;
  const int tile = rem & 63;
  const int tc = tile >> 1, td = tile & 1;
  const float* src = (which == 0 ? Wq : which == 1 ? Wk : Wv) + (long)head * 65536;
  const int tx = threadIdx.x;
  for (int i2 = 0; i2 < 4; ++i2) {
    int i = threadIdx.y + i2 * 8;
    tl[i][tx] = src[(long)(tc * 32 + i) * 64 + td * 32 + tx];
  }
  __syncthreads();
  const long base = (long)which * 1024 + head * 64 + td * 32;
  for (int i2 = 0; i2 < 4; ++i2) {
    int i = threadIdx.y + i2 * 8;
    dst[(base + i) * 1024 + tc * 32 + tx] = f2b(tl[tx][i]);
  }
}

// ---------------- layernorm ----------------
__global__ __launch_bounds__(256)
void layernorm_bf16(const float* __restrict__ x, const float* __restrict__ g,
                    const float* __restrict__ be, short* __restrict__ outp)
{
  const int row = blockIdx.x;
  const int t = threadIdx.x;
  const float4 v = ((const float4*)(x + (long)row * 1024))[t];
  float s = v.x + v.y + v.z + v.w;
  float ss = v.x * v.x + v.y * v.y + v.z * v.z + v.w * v.w;
#pragma unroll
  for (int off = 1; off < 64; off <<= 1) {
    s += __shfl_xor(s, off);
    ss += __shfl_xor(ss, off);
  }
  __shared__ float red[8];
  const int wave = t >> 6, lane = t & 63;
  if (lane == 0) { red[wave] = s; red[4 + wave] = ss; }
  __syncthreads();
  s = red[0] + red[1] + red[2] + red[3];
  ss = red[4] + red[5] + red[6] + red[7];
  const float mu = s * (1.f / 1024.f);
  const float rstd = rsqrtf(ss * (1.f / 1024.f) - mu * mu + 1e-5f);
  const float4 gv = ((const float4*)g)[t];
  const float4 bv = ((const float4*)be)[t];
  short4 ov;
  ov.x = f2b((v.x - mu) * rstd * gv.x + bv.x);
  ov.y = f2b((v.y - mu) * rstd * gv.y + bv.y);
  ov.z = f2b((v.z - mu) * rstd * gv.z + bv.z);
  ov.w = f2b((v.w - mu) * rstd * gv.w + bv.w);
  *(short4*)(outp + (long)row * 1024 + t * 4) = ov;
}

// ---------------- GEMM: C[M][N] = A[M][K] * Bt[N][K]^T, m97 structure ----------------
// EPI 0: Cb = bf16(acc)
// EPI 1: Cf = acc + bias[col] + resid[idx]   (fp32 out)
// EPI 2: Cb = bf16(relu(acc + bias[col]))
template<int EPI>
__global__ __launch_bounds__(256)
void gemm_bt(const short* __restrict__ A, const short* __restrict__ Bt,
             int M, int N, int K,
             short* __restrict__ Cb, float* __restrict__ Cf,
             const float* __restrict__ bias, const float* __restrict__ resid)
{
  __shared__ __align__(16) short As[128 * 64];
  __shared__ __align__(16) short Bs[128 * 64];
  const int tid = threadIdx.x;
  const int lane = tid & 63;
  const int wave = tid >> 6;
  const int l15 = lane & 15, lg = lane >> 4;
  const long m0 = (long)blockIdx.y * 128;
  const long n0 = (long)blockIdx.x * 128;
  const int wr = (wave >> 1) * 64;
  const int wc = (wave & 1) * 64;
  f32x4 acc[4][4] = {};

  const int srow = (wave << 5) + (lane >> 3);  // + c*8
  const int scol = (lane & 7) << 3;
  const short* Ag = A + (m0 + srow) * K + scol;
  const short* Bg = Bt + (n0 + srow) * K + scol;
  short* Asw = &As[(wave << 5) * 64];
  short* Bsw = &Bs[(wave << 5) * 64];

  for (int kt = 0; kt < K; kt += 64) {
#pragma unroll
    for (int c = 0; c < 4; ++c) {
      gload16(Asw + c * 512, Ag + (long)c * 8 * K + kt);
      gload16(Bsw + c * 512, Bg + (long)c * 8 * K + kt);
    }
    __syncthreads();
#pragma unroll
    for (int kk = 0; kk < 64; kk += 32) {
      bf16x8 av[4], bv[4];
#pragma unroll
      for (int i = 0; i < 4; ++i)
        av[i] = *(const bf16x8*)&As[(wr + i * 16 + l15) * 64 + kk + lg * 8];
#pragma unroll
      for (int i = 0; i < 4; ++i)
        bv[i] = *(const bf16x8*)&Bs[(wc + i * 16 + l15) * 64 + kk + lg * 8];
#pragma unroll
      for (int mi = 0; mi < 4; ++mi)
#pragma unroll
        for (int ni = 0; ni < 4; ++ni)
          acc[mi][ni] = __builtin_amdgcn_mfma_f32_16x16x32_bf16(av[mi], bv[ni], acc[mi][ni], 0, 0, 0);
    }
    __syncthreads();
  }

#pragma unroll
  for (int mi = 0; mi < 4; ++mi) {
#pragma unroll
    for (int ni = 0; ni < 4; ++ni) {
      const long col = n0 + wc + ni * 16 + l15;
#pragma unroll
      for (int r = 0; r < 4; ++r) {
        const long row = m0 + wr + mi * 16 + lg * 4 + r;
        const long idx = row * N + col;
        float v = acc[mi][ni][r];
        if (EPI == 0) {
          Cb[idx] = f2b(v);
        } else if (EPI == 1) {
          Cf[idx] = v + bias[col] + resid[idx];
        } else {
          v += bias[col];
          Cb[idx] = f2b(v > 0.f ? v : 0.f);
        }
      }
    }
  }
}

// ---------------- causal flash attention ----------------
// qkv [4096][3072] bf16 (cols: 0..1023 Q, 1024..2047 K, 2048..3071 V; col=head*64+d)
// out [4096][1024] bf16 (concat heads)
__global__ __launch_bounds__(256)
void attn_fwd(const short* __restrict__ qkv, short* __restrict__ outp)
{
  __shared__ __align__(16) short Kl[64 * 64];
  __shared__ __align__(16) short Vt[64 * 64];
  __shared__ __align__(16) short Pl[4][16 * 64];
  const int tid = threadIdx.x;
  const int lane = tid & 63;
  const int wave = tid >> 6;
  const int l15 = lane & 15, lg = lane >> 4;
  const int head = blockIdx.y;
  const int qb = blockIdx.x;
  const int qbase = qb * 64 + wave * 16;

  // Q fragments, pre-scaled by C^-0.5 = 2^-5 (exact in bf16)
  bf16x8 qf[2];
#pragma unroll
  for (int c = 0; c < 2; ++c) {
    const short* p = qkv + (long)(qbase + l15) * 3072 + head * 64 + c * 32 + lg * 8;
    bf16x8 t = *(const bf16x8*)p;
#pragma unroll
    for (int j = 0; j < 8; ++j) t[j] = f2b(b2f(t[j]) * 0.03125f);
    qf[c] = t;
  }

  float m_r[4] = {-INFINITY, -INFINITY, -INFINITY, -INFINITY};
  float l_r[4] = {0.f, 0.f, 0.f, 0.f};
  f32x4 o[4] = {};

  for (int kv0 = 0; kv0 <= qb * 64; kv0 += 64) {
    __syncthreads();  // protect LDS reuse
    // stage K (swizzled rows) and V^T (swizzled rows)
#pragma unroll
    for (int it = 0; it < 2; ++it) {
      int id = it * 256 + tid;       // 0..511
      int key = id >> 3, dc = id & 7;
      const short* ksrc = qkv + (long)(kv0 + key) * 3072 + 1024 + head * 64 + dc * 8;
      bf16x8 kvv = *(const bf16x8*)ksrc;
      int kbyte = key * 128 + ((dc * 16) ^ ((key & 7) << 4));
      *(bf16x8*)((char*)Kl + kbyte) = kvv;
      const short* vsrc = qkv + (long)(kv0 + key) * 3072 + 2048 + head * 64 + dc * 8;
      bf16x8 vv = *(const bf16x8*)vsrc;
#pragma unroll
      for (int j = 0; j < 8; ++j) {
        int d = dc * 8 + j;
        int vbyte = d * 128 + ((key * 2) ^ ((d & 7) << 4));
        *(short*)((char*)Vt + vbyte) = vv[j];
      }
    }
    __syncthreads();

    // S = (Q/32) K^T for 4 sub-blocks of 16 keys
    f32x4 S[4];
#pragma unroll
    for (int sb = 0; sb < 4; ++sb) {
      const int ks0 = kv0 + sb * 16;
      if (ks0 > qbase + 15) {  // fully masked for this wave
        S[sb] = f32x4{-INFINITY, -INFINITY, -INFINITY, -INFINITY};
        continue;
      }
      f32x4 s = {};
      const int krow = sb * 16 + l15;
#pragma unroll
      for (int c = 0; c < 2; ++c) {
        int kbyte = krow * 128 + (((c * 64) + lg * 16) ^ ((krow & 7) << 4));
        bf16x8 kf = *(const bf16x8*)((const char*)Kl + kbyte);
        s = __builtin_amdgcn_mfma_f32_16x16x32_bf16(qf[c], kf, s, 0, 0, 0);
      }
      if (ks0 + 15 > qbase) {  // diagonal region: per-element mask
#pragma unroll
        for (int r = 0; r < 4; ++r)
          if (ks0 + l15 > qbase + lg * 4 + r) s[r] = -INFINITY;
      }
      S[sb] = s;
    }

    // online softmax (rows spread over 16-lane groups; 4 rows/lane in regs)
    float sc[4];
#pragma unroll
    for (int r = 0; r < 4; ++r) {
      float mb = fmaxf(fmaxf(S[0][r], S[1][r]), fmaxf(S[2][r], S[3][r]));
      mb = fmaxf(mb, __shfl_xor(mb, 1));
      mb = fmaxf(mb, __shfl_xor(mb, 2));
      mb = fmaxf(mb, __shfl_xor(mb, 4));
      mb = fmaxf(mb, __shfl_xor(mb, 8));
      float mn = fmaxf(m_r[r], mb);
      sc[r] = expf(m_r[r] - mn);
      m_r[r] = mn;
    }
#pragma unroll
    for (int sb = 0; sb < 4; ++sb)
#pragma unroll
      for (int r = 0; r < 4; ++r)
        S[sb][r] = expf(S[sb][r] - m_r[r]);
#pragma unroll
    for (int r = 0; r < 4; ++r) {
      float s4 = S[0][r] + S[1][r] + S[2][r] + S[3][r];
      s4 += __shfl_xor(s4, 1);
      s4 += __shfl_xor(s4, 2);
      s4 += __shfl_xor(s4, 4);
      s4 += __shfl_xor(s4, 8);
      l_r[r] = l_r[r] * sc[r] + s4;
#pragma unroll
      for (int n = 0; n < 4; ++n) o[n][r] *= sc[r];
    }

    // P -> LDS (per-wave scratch, swizzled) -> A-fragments
    short* Pw = Pl[wave];
#pragma unroll
    for (int sb = 0; sb < 4; ++sb)
#pragma unroll
      for (int r = 0; r < 4; ++r) {
        int qrow = lg * 4 + r, key = sb * 16 + l15;
        int pbyte = qrow * 128 + ((key * 2) ^ ((qrow & 7) << 4));
        *(short*)((char*)Pw + pbyte) = f2b(S[sb][r]);
      }
    bf16x8 pa[2];
#pragma unroll
    for (int c = 0; c < 2; ++c) {
      int pbyte = l15 * 128 + (((c * 64) + lg * 16) ^ ((l15 & 7) << 4));
      pa[c] = *(const bf16x8*)((const char*)Pw + pbyte);
    }
    // O += P V
#pragma unroll
    for (int c = 0; c < 2; ++c)
#pragma unroll
      for (int n = 0; n < 4; ++n) {
        int d = n * 16 + l15;
        int vbyte = d * 128 + (((c * 64) + lg * 16) ^ ((d & 7) << 4));
        bf16x8 vb = *(const bf16x8*)((const char*)Vt + vbyte);
        o[n] = __builtin_amdgcn_mfma_f32_16x16x32_bf16(pa[c], vb, o[n], 0, 0, 0);
      }
  }

#pragma unroll
  for (int n = 0; n < 4; ++n)
#pragma unroll
    for (int r = 0; r < 4; ++r) {
      long q = qbase + lg * 4 + r;
      int d = n * 16 + l15;
      outp[q * 1024 + head * 64 + d] = f2b(o[n][r] / l_r[r]);
    }
}

// ---------------- launcher ----------------
extern "C" void kernel_launch(void* const* d_in, const int* in_sizes, int n_in,
                              void* d_out, int out_size, void* d_ws, size_t ws_size,
                              hipStream_t stream)
{
  (void)in_sizes; (void)n_in; (void)out_size; (void)ws_size;
  const float* x   = (const float*)d_in[0];
  const float* Wq  = (const float*)d_in[1];
  const float* Wk  = (const float*)d_in[2];
  const float* Wv  = (const float*)d_in[3];
  const float* Wp  = (const float*)d_in[4];
  const float* bp  = (const float*)d_in[5];
  const float* W1  = (const float*)d_in[6];
  const float* b1  = (const float*)d_in[7];
  const float* W2  = (const float*)d_in[8];
  const float* b2  = (const float*)d_in[9];
  const float* g1  = (const float*)d_in[10];
  const float* be1 = (const float*)d_in[11];
  const float* g2  = (const float*)d_in[12];
  const float* be2 = (const float*)d_in[13];
  float* out = (float*)d_out;

  char* ws = (char*)d_ws;
  const size_t MB = 1ull << 20;
  short* WqkvT = (short*)(ws + 0 * MB);    // [3072][1024] bf16, 6MB
  short* WpT   = (short*)(ws + 6 * MB);    // [1024][1024] bf16, 2MB
  short* W1T   = (short*)(ws + 8 * MB);    // [4096][1024] bf16, 8MB
  short* W2T   = (short*)(ws + 16 * MB);   // [1024][4096] bf16, 8MB
  short* hbuf  = (short*)(ws + 24 * MB);   // [4096][1024] bf16 (h, then h2), 8MB
  short* qkvb  = (short*)(ws + 32 * MB);   // [4096][3072] bf16; later ff1 [4096][4096], 32MB span
  short* attnb = (short*)(ws + 56 * MB);   // [4096][1024] bf16, 8MB
  float* x1    = (float*)(ws + 64 * MB);   // [4096][1024] f32, 16MB (end: 80MB)

  // weight conversion / packing (bf16, B^T layouts)
  qkv_pack<<<3072, dim3(32, 8), 0, stream>>>(Wq, Wk, Wv, WqkvT);
  transpose_conv<<<dim3(32, 32), dim3(32, 8), 0, stream>>>(Wp, WpT, 1024, 1024);
  transpose_conv<<<dim3(128, 32), dim3(32, 8), 0, stream>>>(W1, W1T, 1024, 4096);
  transpose_conv<<<dim3(32, 128), dim3(32, 8), 0, stream>>>(W2, W2T, 4096, 1024);

  // LN1 -> h (bf16)
  layernorm_bf16<<<4096, 256, 0, stream>>>(x, g1, be1, hbuf);
  // QKV: [4096][3072]
  gemm_bt<0><<<dim3(24, 32), 256, 0, stream>>>(hbuf, WqkvT, 4096, 3072, 1024,
                                               qkvb, nullptr, nullptr, nullptr);
  // attention
  attn_fwd<<<dim3(64, 16), 256, 0, stream>>>(qkvb, attnb);
  // proj + bias + residual(x) -> x1 (fp32)
  gemm_bt<1><<<dim3(8, 32), 256, 0, stream>>>(attnb, WpT, 4096, 1024, 1024,
                                              nullptr, x1, bp, x);
  // LN2 -> h2 (bf16, reuses hbuf)
  layernorm_bf16<<<4096, 256, 0, stream>>>(x1, g2, be2, hbuf);
  // FFN1 + bias + relu -> ff1 (bf16, reuses qkv span)
  gemm_bt<2><<<dim3(32, 32), 256, 0, stream>>>(hbuf, W1T, 4096, 4096, 1024,
                                               qkvb, nullptr, b1, nullptr);
  // FFN2 + bias + residual(x1) -> out (fp32)
  gemm_bt<1><<<dim3(8, 32), 256, 0, stream>>>(qkvb, W2T, 4096, 1024, 4096,
                                              nullptr, out, b2, x1);
}

// Round 2
// 378.378 us; speedup vs baseline: 1.4851x; 1.4851x over previous
//
#include <hip/hip_runtime.h>
#include <cstdint>

typedef __attribute__((ext_vector_type(8))) short bf16x8;
typedef __attribute__((ext_vector_type(4))) float f32x4;
typedef __attribute__((ext_vector_type(16))) float f32x16;
typedef __attribute__((ext_vector_type(4))) unsigned int u32x4;

__device__ __forceinline__ short f2b(float f) {
  unsigned u = __builtin_bit_cast(unsigned, f);
  unsigned r = (u + 0x7fffu + ((u >> 16) & 1u)) >> 16;
  return (short)(unsigned short)r;
}
__device__ __forceinline__ float b2f(short s) {
  unsigned u = ((unsigned)(unsigned short)s) << 16;
  return __builtin_bit_cast(float, u);
}

__device__ __forceinline__ void gload16(void* lds_dst, const void* gsrc) {
  __builtin_amdgcn_global_load_lds(
      (const __attribute__((address_space(1))) void*)gsrc,
      (__attribute__((address_space(3))) void*)lds_dst, 16, 0, 0);
}

__device__ __forceinline__ unsigned cvtpk(float a, float b) {
  unsigned r;
  asm("v_cvt_pk_bf16_f32 %0, %1, %2" : "=v"(r) : "v"(a), "v"(b));
  return r;
}
__device__ __forceinline__ unsigned shflx32(unsigned v) {
  return (unsigned)__shfl_xor((int)v, 32);
}

// ---------------- weight conversion ----------------
__global__ void transpose_conv(const float* __restrict__ src, short* __restrict__ dst,
                               int rows, int cols)
{
  __shared__ float tl[32][33];
  const int bx = blockIdx.x, by = blockIdx.y;
  const int tx = threadIdx.x;
  const int x = bx * 32 + tx;
  for (int i2 = 0; i2 < 4; ++i2) {
    int i = threadIdx.y + i2 * 8;
    tl[i][tx] = src[(long)(by * 32 + i) * cols + x];
  }
  __syncthreads();
  const int xo = by * 32 + tx;
  for (int i2 = 0; i2 < 4; ++i2) {
    int i = threadIdx.y + i2 * 8;
    dst[(long)(bx * 32 + i) * rows + xo] = f2b(tl[tx][i]);
  }
}

__global__ void qkv_pack(const float* __restrict__ Wq, const float* __restrict__ Wk,
                         const float* __restrict__ Wv, short* __restrict__ dst)
{
  __shared__ float tl[32][33];
  const int t = blockIdx.x;
  const int which = t >> 10;
  const int rem = t & 1023;
  const int head = rem >> 6;
  const int tile = rem & 63;
  const int tc = tile >> 1, td = tile & 1;
  const float* src = (which == 0 ? Wq : which == 1 ? Wk : Wv) + (long)head * 65536;
  const int tx = threadIdx.x;
  for (int i2 = 0; i2 < 4; ++i2) {
    int i = threadIdx.y + i2 * 8;
    tl[i][tx] = src[(long)(tc * 32 + i) * 64 + td * 32 + tx];
  }
  __syncthreads();
  const long base = (long)which * 1024 + head * 64 + td * 32;
  for (int i2 = 0; i2 < 4; ++i2) {
    int i = threadIdx.y + i2 * 8;
    dst[(base + i) * 1024 + tc * 32 + tx] = f2b(tl[tx][i]);
  }
}

// V part of qkv [4096][3072] -> Vt [16][64][4096] bf16
__global__ void vtrans(const short* __restrict__ qkv, short* __restrict__ Vt)
{
  __shared__ short tl[32][33];
  const int t0 = blockIdx.x * 32;
  const int c0 = blockIdx.y * 32;
  const int head = c0 >> 6, d0 = c0 & 63;
  const int tx = threadIdx.x;
#pragma unroll
  for (int i2 = 0; i2 < 4; ++i2) {
    int i = threadIdx.y + i2 * 8;
    tl[i][tx] = qkv[(long)(t0 + i) * 3072 + 2048 + c0 + tx];
  }
  __syncthreads();
#pragma unroll
  for (int i2 = 0; i2 < 4; ++i2) {
    int i = threadIdx.y + i2 * 8;
    Vt[(long)head * 262144 + (long)(d0 + i) * 4096 + t0 + tx] = tl[tx][i];
  }
}

// ---------------- layernorm ----------------
__global__ __launch_bounds__(256)
void layernorm_bf16(const float* __restrict__ x, const float* __restrict__ g,
                    const float* __restrict__ be, short* __restrict__ outp)
{
  const int row = blockIdx.x;
  const int t = threadIdx.x;
  const float4 v = ((const float4*)(x + (long)row * 1024))[t];
  float s = v.x + v.y + v.z + v.w;
  float ss = v.x * v.x + v.y * v.y + v.z * v.z + v.w * v.w;
#pragma unroll
  for (int off = 1; off < 64; off <<= 1) {
    s += __shfl_xor(s, off);
    ss += __shfl_xor(ss, off);
  }
  __shared__ float red[8];
  const int wave = t >> 6, lane = t & 63;
  if (lane == 0) { red[wave] = s; red[4 + wave] = ss; }
  __syncthreads();
  s = red[0] + red[1] + red[2] + red[3];
  ss = red[4] + red[5] + red[6] + red[7];
  const float mu = s * (1.f / 1024.f);
  const float rstd = rsqrtf(ss * (1.f / 1024.f) - mu * mu + 1e-5f);
  const float4 gv = ((const float4*)g)[t];
  const float4 bv = ((const float4*)be)[t];
  short4 ov;
  ov.x = f2b((v.x - mu) * rstd * gv.x + bv.x);
  ov.y = f2b((v.y - mu) * rstd * gv.y + bv.y);
  ov.z = f2b((v.z - mu) * rstd * gv.z + bv.z);
  ov.w = f2b((v.w - mu) * rstd * gv.w + bv.w);
  *(short4*)(outp + (long)row * 1024 + t * 4) = ov;
}

// ---------------- GEMM (m97 structure) ----------------
template<int EPI>
__global__ __launch_bounds__(256)
void gemm_bt(const short* __restrict__ A, const short* __restrict__ Bt,
             int M, int N, int K,
             short* __restrict__ Cb, float* __restrict__ Cf,
             const float* __restrict__ bias, const float* __restrict__ resid)
{
  __shared__ __align__(16) short As[128 * 64];
  __shared__ __align__(16) short Bs[128 * 64];
  const int tid = threadIdx.x;
  const int lane = tid & 63;
  const int wave = tid >> 6;
  const int l15 = lane & 15, lg = lane >> 4;
  const long m0 = (long)blockIdx.y * 128;
  const long n0 = (long)blockIdx.x * 128;
  const int wr = (wave >> 1) * 64;
  const int wc = (wave & 1) * 64;
  f32x4 acc[4][4] = {};

  const int srow = (wave << 5) + (lane >> 3);
  const int scol = (lane & 7) << 3;
  const short* Ag = A + (m0 + srow) * K + scol;
  const short* Bg = Bt + (n0 + srow) * K + scol;
  short* Asw = &As[(wave << 5) * 64];
  short* Bsw = &Bs[(wave << 5) * 64];

  for (int kt = 0; kt < K; kt += 64) {
#pragma unroll
    for (int c = 0; c < 4; ++c) {
      gload16(Asw + c * 512, Ag + (long)c * 8 * K + kt);
      gload16(Bsw + c * 512, Bg + (long)c * 8 * K + kt);
    }
    __syncthreads();
#pragma unroll
    for (int kk = 0; kk < 64; kk += 32) {
      bf16x8 av[4], bv[4];
#pragma unroll
      for (int i = 0; i < 4; ++i)
        av[i] = *(const bf16x8*)&As[(wr + i * 16 + l15) * 64 + kk + lg * 8];
#pragma unroll
      for (int i = 0; i < 4; ++i)
        bv[i] = *(const bf16x8*)&Bs[(wc + i * 16 + l15) * 64 + kk + lg * 8];
#pragma unroll
      for (int mi = 0; mi < 4; ++mi)
#pragma unroll
        for (int ni = 0; ni < 4; ++ni)
          acc[mi][ni] = __builtin_amdgcn_mfma_f32_16x16x32_bf16(av[mi], bv[ni], acc[mi][ni], 0, 0, 0);
    }
    __syncthreads();
  }

#pragma unroll
  for (int mi = 0; mi < 4; ++mi) {
#pragma unroll
    for (int ni = 0; ni < 4; ++ni) {
      const long col = n0 + wc + ni * 16 + l15;
#pragma unroll
      for (int r = 0; r < 4; ++r) {
        const long row = m0 + wr + mi * 16 + lg * 4 + r;
        const long idx = row * N + col;
        float v = acc[mi][ni][r];
        if (EPI == 0) {
          Cb[idx] = f2b(v);
        } else if (EPI == 1) {
          Cf[idx] = v + bias[col] + resid[idx];
        } else {
          v += bias[col];
          Cb[idx] = f2b(v > 0.f ? v : 0.f);
        }
      }
    }
  }
}

// ---------------- flash attention, swapped-QK^T 32x32 structure ----------------
// Stage a 64-row x 64-col bf16 tile into LDS with XOR-swizzled chunks.
// LDS byte(row, c) = row*128 + 16*(c ^ (row&7)); staged linearly with
// pre-swizzled global chunk c = (l&7)^(l>>3).
__device__ __forceinline__ void stage_tile(short* lds, const short* gbase,
                                           long rstride, int wave, int lane)
{
  const int rloc = lane >> 3;
  const int chunk = (lane & 7) ^ rloc;
#pragma unroll
  for (int it = 0; it < 4; ++it) {
    const int row = wave * 32 + it * 8 + rloc;
    gload16(lds + (wave * 32 + it * 8) * 64, gbase + (long)row * rstride + chunk * 8);
  }
}

__global__ __launch_bounds__(128)
void attn_fwd2(const short* __restrict__ qkv, const short* __restrict__ Vt,
               short* __restrict__ outp)
{
  __shared__ __align__(16) short Ksm[2][64 * 64];
  __shared__ __align__(16) short Vsm[2][64 * 64];
  __shared__ __align__(16) short Qsm[64 * 64];
  __shared__ float scl[64];
  const int tid = threadIdx.x;
  const int lane = tid & 63;
  const int wave = tid >> 6;          // 0..1
  const int head = blockIdx.y;
  const int l31 = lane & 31;
  const int h = lane >> 5;
  const bool lolane = (h == 0);

  const short* Qg = qkv + head * 64;
  const short* Kg = qkv + 1024 + head * 64;
  const short* Vg = Vt + (long)head * 262144;

  for (int ph = 0; ph < 2; ++ph) {
    const int qsuper = ph ? (63 - (int)blockIdx.x) : (int)blockIdx.x;
    const int q0 = qsuper * 64 + wave * 32;
    const int q = q0 + l31;
    const int nt = qsuper + 1;

    // prologue: stage Q tile + kv tile 0
    stage_tile(Qsm, Qg + (long)(qsuper * 64) * 3072, 3072, wave, lane);
    stage_tile(Ksm[0], Kg, 3072, wave, lane);
    stage_tile(Vsm[0], Vg, 4096, wave, lane);
    __syncthreads();

    // Q fragments (B-operand: B[d][q], q = l&31), pre-scaled by 2^-5 (exact)
    bf16x8 qf[4];
#pragma unroll
    for (int d = 0; d < 4; ++d) {
      const int row = wave * 32 + l31;
      const int ck = (d * 2 + h) ^ (row & 7);
      bf16x8 tq = *(const bf16x8*)((const char*)Qsm + row * 128 + ck * 16);
#pragma unroll
      for (int j = 0; j < 8; ++j) tq[j] = f2b(b2f(tq[j]) * 0.03125f);
      qf[d] = tq;
    }

    float m_r = -INFINITY, l_r = 0.f;
    f32x16 o0 = {}, o1 = {};

    for (int t = 0; t < nt; ++t) {
      const int cur = t & 1;
      if (t + 1 < nt) {
        const long kv1 = (long)(t + 1) * 64;
        stage_tile(Ksm[cur ^ 1], Kg + kv1 * 3072, 3072, wave, lane);
        stage_tile(Vsm[cur ^ 1], Vg + kv1, 4096, wave, lane);
      }
      const int kv0 = t * 64;
      const short* Ks = Ksm[cur];
      const short* Vs = Vsm[cur];
#pragma unroll
      for (int ks = 0; ks < 2; ++ks) {
        if (kv0 + ks * 32 > q0 + 31) continue;  // fully masked (wave-uniform)
        // S^T = K . Q^T : lane owns q = l&31; holds 16 k's: (r&3)+8*(r>>2)+4*h
        f32x16 s = {};
#pragma unroll
        for (int d = 0; d < 4; ++d) {
          const int row = ks * 32 + l31;
          const int ck = (d * 2 + h) ^ (row & 7);
          bf16x8 kf = *(const bf16x8*)((const char*)Ks + row * 128 + ck * 16);
          s = __builtin_amdgcn_mfma_f32_32x32x16_bf16(kf, qf[d], s, 0, 0, 0);
        }
        if (kv0 + ks * 32 + 31 > q0) {  // diagonal: per-element causal mask
          const int kb = kv0 + ks * 32 + 4 * h;
#pragma unroll
          for (int r = 0; r < 16; ++r) {
            const int k = kb + (r & 3) + 8 * (r >> 2);
            if (k > q) s[r] = -INFINITY;
          }
        }
        // row max: in-register tree + cross-half swap
        float m01 = fmaxf(s[0], s[1]),  m23 = fmaxf(s[2], s[3]);
        float m45 = fmaxf(s[4], s[5]),  m67 = fmaxf(s[6], s[7]);
        float m89 = fmaxf(s[8], s[9]),  mab = fmaxf(s[10], s[11]);
        float mcd = fmaxf(s[12], s[13]), mef = fmaxf(s[14], s[15]);
        float mb = fmaxf(fmaxf(fmaxf(m01, m23), fmaxf(m45, m67)),
                         fmaxf(fmaxf(m89, mab), fmaxf(mcd, mef)));
        mb = fmaxf(mb, __shfl_xor(mb, 32));
        if (!__all(mb <= m_r + 8.f)) {   // defer-max: rescale only when needed
          const float mn = fmaxf(m_r, mb);
          const float sc = __expf(m_r - mn);
          m_r = mn;
          l_r *= sc;
          scl[wave * 32 + l31] = sc;
          asm volatile("s_waitcnt lgkmcnt(0)" ::: "memory");
#pragma unroll
          for (int r = 0; r < 16; ++r) {
            const float sb = scl[wave * 32 + ((r & 3) + 8 * (r >> 2) + 4 * h)];
            o0[r] *= sb;
            o1[r] *= sb;
          }
        }
#pragma unroll
        for (int r = 0; r < 16; ++r) s[r] = __expf(s[r] - m_r);
        {
          float a = (s[0] + s[1]) + (s[2] + s[3]);
          float b = (s[4] + s[5]) + (s[6] + s[7]);
          float c = (s[8] + s[9]) + (s[10] + s[11]);
          float d = (s[12] + s[13]) + (s[14] + s[15]);
          float ps = (a + b) + (c + d);
          ps += __shfl_xor(ps, 32);
          l_r += ps;
        }
        // pack P into A-fragments (A[q][k'], q = l&31)
        const unsigned P0 = cvtpk(s[0], s[1]),   P1 = cvtpk(s[2], s[3]);
        const unsigned P2 = cvtpk(s[4], s[5]),   P3 = cvtpk(s[6], s[7]);
        const unsigned P4 = cvtpk(s[8], s[9]),   P5 = cvtpk(s[10], s[11]);
        const unsigned P6 = cvtpk(s[12], s[13]), P7 = cvtpk(s[14], s[15]);
        const unsigned P0x = shflx32(P0), P1x = shflx32(P1);
        const unsigned P2x = shflx32(P2), P3x = shflx32(P3);
        const unsigned P4x = shflx32(P4), P5x = shflx32(P5);
        const unsigned P6x = shflx32(P6), P7x = shflx32(P7);
        u32x4 fa0, fa1;
        fa0[0] = lolane ? P0 : P2x;  fa0[1] = lolane ? P1 : P3x;
        fa0[2] = lolane ? P0x : P2;  fa0[3] = lolane ? P1x : P3;
        fa1[0] = lolane ? P4 : P6x;  fa1[1] = lolane ? P5 : P7x;
        fa1[2] = lolane ? P4x : P6;  fa1[3] = lolane ? P5x : P7;
        const bf16x8 pa0 = __builtin_bit_cast(bf16x8, fa0);
        const bf16x8 pa1 = __builtin_bit_cast(bf16x8, fa1);
        // O += P V   (B[k'][d] from Vt tile rows = d)
#pragma unroll
        for (int kb2 = 0; kb2 < 2; ++kb2) {
          const bf16x8 pa = kb2 ? pa1 : pa0;
#pragma unroll
          for (int nb = 0; nb < 2; ++nb) {
            const int row = nb * 32 + l31;
            const int ck = (ks * 4 + kb2 * 2 + h) ^ (row & 7);
            const bf16x8 vf = *(const bf16x8*)((const char*)Vs + row * 128 + ck * 16);
            if (nb == 0) o0 = __builtin_amdgcn_mfma_f32_32x32x16_bf16(pa, vf, o0, 0, 0, 0);
            else         o1 = __builtin_amdgcn_mfma_f32_32x32x16_bf16(pa, vf, o1, 0, 0, 0);
          }
        }
      }
      __syncthreads();
    }

    // epilogue: broadcast l, normalize, store
    scl[wave * 32 + l31] = l_r;
    asm volatile("s_waitcnt lgkmcnt(0)" ::: "memory");
#pragma unroll
    for (int r = 0; r < 16; ++r) {
      const int qo = (r & 3) + 8 * (r >> 2) + 4 * h;
      const float lb = scl[wave * 32 + qo];
      const float inv = 1.0f / lb;
      const long qr = q0 + qo;
      outp[qr * 1024 + head * 64 + l31] = f2b(o0[r] * inv);
      outp[qr * 1024 + head * 64 + 32 + l31] = f2b(o1[r] * inv);
    }
    __syncthreads();  // protect LDS before next phase restage
  }
}

// ---------------- launcher ----------------
extern "C" void kernel_launch(void* const* d_in, const int* in_sizes, int n_in,
                              void* d_out, int out_size, void* d_ws, size_t ws_size,
                              hipStream_t stream)
{
  (void)in_sizes; (void)n_in; (void)out_size; (void)ws_size;
  const float* x   = (const float*)d_in[0];
  const float* Wq  = (const float*)d_in[1];
  const float* Wk  = (const float*)d_in[2];
  const float* Wv  = (const float*)d_in[3];
  const float* Wp  = (const float*)d_in[4];
  const float* bp  = (const float*)d_in[5];
  const float* W1  = (const float*)d_in[6];
  const float* b1  = (const float*)d_in[7];
  const float* W2  = (const float*)d_in[8];
  const float* b2  = (const float*)d_in[9];
  const float* g1  = (const float*)d_in[10];
  const float* be1 = (const float*)d_in[11];
  const float* g2  = (const float*)d_in[12];
  const float* be2 = (const float*)d_in[13];
  float* out = (float*)d_out;

  char* ws = (char*)d_ws;
  const size_t MB = 1ull << 20;
  short* WqkvT = (short*)(ws + 0 * MB);    // [3072][1024] bf16, 6MB
  short* WpT   = (short*)(ws + 6 * MB);    // [1024][1024] bf16, 2MB
  short* W1T   = (short*)(ws + 8 * MB);    // [4096][1024] bf16, 8MB
  short* W2T   = (short*)(ws + 16 * MB);   // [1024][4096] bf16, 8MB
  short* hbuf  = (short*)(ws + 24 * MB);   // [4096][1024] bf16 (h, then h2), 8MB
  short* qkvb  = (short*)(ws + 32 * MB);   // [4096][3072] bf16; later ff1 spans 32-64MB
  short* attnb = (short*)(ws + 56 * MB);   // [4096][1024] bf16, 8MB
  float* x1    = (float*)(ws + 64 * MB);   // [4096][1024] f32, 16MB (end: 80MB)
  short* Vtb   = (short*)(ws + 64 * MB);   // [16][64][4096] bf16, 8MB (dead before x1 write)

  qkv_pack<<<3072, dim3(32, 8), 0, stream>>>(Wq, Wk, Wv, WqkvT);
  transpose_conv<<<dim3(32, 32), dim3(32, 8), 0, stream>>>(Wp, WpT, 1024, 1024);
  transpose_conv<<<dim3(128, 32), dim3(32, 8), 0, stream>>>(W1, W1T, 1024, 4096);
  transpose_conv<<<dim3(32, 128), dim3(32, 8), 0, stream>>>(W2, W2T, 4096, 1024);

  layernorm_bf16<<<4096, 256, 0, stream>>>(x, g1, be1, hbuf);
  gemm_bt<0><<<dim3(24, 32), 256, 0, stream>>>(hbuf, WqkvT, 4096, 3072, 1024,
                                               qkvb, nullptr, nullptr, nullptr);
  vtrans<<<dim3(128, 32), dim3(32, 8), 0, stream>>>(qkvb, Vtb);
  attn_fwd2<<<dim3(32, 16), 128, 0, stream>>>(qkvb, Vtb, attnb);
  gemm_bt<1><<<dim3(8, 32), 256, 0, stream>>>(attnb, WpT, 4096, 1024, 1024,
                                              nullptr, x1, bp, x);
  layernorm_bf16<<<4096, 256, 0, stream>>>(x1, g2, be2, hbuf);
  gemm_bt<2><<<dim3(32, 32), 256, 0, stream>>>(hbuf, W1T, 4096, 4096, 1024,
                                               qkvb, nullptr, b1, nullptr);
  gemm_bt<1><<<dim3(8, 32), 256, 0, stream>>>(qkvb, W2T, 4096, 1024, 4096,
                                              nullptr, out, b2, x1);
}